// Round 7
// baseline (527.660 us; speedup 1.0000x reference)
//
#include <hip/hip_runtime.h>

#define N_FUNC 10000
#define N_IN   2000
#define N_OUT  2000
#define CCH    8
#define K_FF   16
#define E_FF    160000   // ff edges: dst[e] = e/16 (structural), src random func
#define E_W1    168000   // ff+if edges (dst < N_FUNC)
#define E_IF    8000
#define BATCH   64
#define EPS_LN  1e-5f
#define IF_CAP  16        // max if-in-degree of a func node (mean 0.8)
#define HROW    (BATCH * CCH)   // Hsum row: 512 ushorts (bf16) = 1 KB per node
#define NBLK    1024      // 4 blocks/CU x 256 CUs co-resident (60 VGPR, validated R3)
#define NWAVE   (NBLK * 4)

typedef float f2 __attribute__((ext_vector_type(2)));   // -> v_pk_fma_f32

// ---- bf16 helpers (fp32 math everywhere; RNE on store) ----
__device__ __forceinline__ f2 bfpair(unsigned int u) {   // packed pair -> 2 floats
    f2 r;
    r.x = __builtin_bit_cast(float, u << 16);
    r.y = __builtin_bit_cast(float, u & 0xffff0000u);
    return r;
}
__device__ __forceinline__ unsigned int bfpack2(float f0, float f1) {
    unsigned int x0 = __builtin_bit_cast(unsigned int, f0);
    unsigned int x1 = __builtin_bit_cast(unsigned int, f1);
    unsigned int r0 = (x0 + 0x7fffu + ((x0 >> 16) & 1u)) >> 16;
    unsigned int r1 = (x1 + 0x7fffu + ((x1 >> 16) & 1u)) & 0xffff0000u;
    return r0 | r1;
}

// fast GELU (validated: absmax unchanged vs exact erf)
__device__ __forceinline__ float fast_gelu(float x) {
    float x2 = x * x;
    float u  = x * __builtin_fmaf(0.044715f, x2, 1.0f);
    float e  = exp2f(-2.3022080f * u);     // sigmoid(1.5957691*u)
    return x * (1.0f / (1.0f + e));
}

// ---- grid barrier v2: split arrive/release lines, long-sleep polling ----
// bar[0]  : arrival counter (atomicAdd, device scope)
// bar[32] : release generation (single writer per phase = last arriver)
// R3's version (s_sleep(1), poll the RMW line) cost ~170 us/barrier from
// 16 agent-scope loads/cycle on one cacheline; this drops polling 32x and
// removes RMW interference from the polled line.
__device__ __forceinline__ void gsync(unsigned* bar, unsigned phase) {
    __syncthreads();
    if (threadIdx.x == 0) {
        __threadfence();                                  // release our stores
        unsigned prev = atomicAdd(bar, 1u);               // device-scope RMW
        if (prev + 1 == phase * NBLK) {
            __hip_atomic_store(bar + 32, phase, __ATOMIC_RELAXED,
                               __HIP_MEMORY_SCOPE_AGENT); // open the gate
        } else {
            while (__hip_atomic_load(bar + 32, __ATOMIC_RELAXED,
                                     __HIP_MEMORY_SCOPE_AGENT) < phase)
                __builtin_amdgcn_s_sleep(32);             // ~2048 cycles/poll
        }
    }
    __syncthreads();
    __threadfence();                                      // acquire
}

// ---------------- shared pieces (float2-packed), round-0 dataflow ----------------

__device__ __forceinline__ void if_accum(
        f2* __restrict__ acc2, const float* __restrict__ xT,
        const float* __restrict__ w1, const float* __restrict__ b3,
        const int* __restrict__ if_cnt, const int* __restrict__ if_bkt,
        int f, int lane, float lf) {
    int icnt = if_cnt[f];
    for (int j = 0; j < icnt; j++) {
        int e = if_bkt[f * IF_CAP + j];
        int ii = (e - E_FF) >> 2;
        float xv = xT[ii * BATCH + lane] + lf * b3[e];
        f2 xv2; xv2.x = xv; xv2.y = xv;
        const f2* w1v = (const f2*)(w1 + (size_t)e * CCH);
        #pragma unroll
        for (int q = 0; q < 4; q++) acc2[q] += xv2 * w1v[q];
    }
}

__device__ __forceinline__ void ln_gelu(
        const f2* __restrict__ acc2, const float* __restrict__ gamma,
        const float* __restrict__ beta, int f, f2* __restrict__ h2) {
    float mu = 0.f;
    #pragma unroll
    for (int q = 0; q < 4; q++) mu += acc2[q].x + acc2[q].y;
    mu *= 0.125f;
    float var = 0.f;
    #pragma unroll
    for (int q = 0; q < 4; q++) {
        float dx = acc2[q].x - mu, dy = acc2[q].y - mu;
        var += dx * dx + dy * dy;
    }
    var *= 0.125f;
    float rs = rsqrtf(var + EPS_LN);
    const f2* gv = (const f2*)(gamma + (size_t)f * CCH);
    const f2* bv = (const f2*)(beta + (size_t)f * CCH);
    f2 mu2; mu2.x = mu; mu2.y = mu;
    f2 rs2; rs2.x = rs; rs2.y = rs;
    #pragma unroll
    for (int q = 0; q < 4; q++) {
        f2 g = (acc2[q] - mu2) * rs2 * gv[q] + bv[q];
        h2[q].x = fast_gelu(g.x);
        h2[q].y = fast_gelu(g.y);
    }
}

// gather-form h for node f, coefficient lf = (layer_idx-1):
// ff in-edge value = lf*b3[e] + dot8(w3[e], Hsum_old[src[e]])
__device__ __forceinline__ void compute_h_gather(
        const unsigned short* __restrict__ Hold, const float* __restrict__ xT,
        const float* __restrict__ w1, const float* __restrict__ b1,
        const float* __restrict__ gamma, const float* __restrict__ beta,
        const float* __restrict__ w3, const float* __restrict__ b3,
        const int* __restrict__ esrc, const int* __restrict__ if_cnt,
        const int* __restrict__ if_bkt, int f, int lane, float lf,
        f2* __restrict__ h2) {
    int srcs[K_FF];
    #pragma unroll
    for (int k = 0; k < K_FF; k++) srcs[k] = esrc[f * K_FF + k];
    // 16 coalesced 1 KB gathers of Hsum rows (bf16, 16 B/lane), all in flight
    uint4 hrow[K_FF];
    #pragma unroll
    for (int k = 0; k < K_FF; k++)
        hrow[k] = *(const uint4*)(Hold + (size_t)srcs[k] * HROW + lane * CCH);

    const f2* b1v = (const f2*)(b1 + (size_t)f * CCH);
    f2 acc2[4];
    #pragma unroll
    for (int q = 0; q < 4; q++) acc2[q] = b1v[q];

    #pragma unroll
    for (int k = 0; k < K_FF; k++) {
        int e = f * K_FF + k;
        const f2* w3v = (const f2*)(w3 + (size_t)e * CCH);   // contiguous rows
        const f2* w1v = (const f2*)(w1 + (size_t)e * CCH);
        f2 d = bfpair(hrow[k].x) * w3v[0];
        d += bfpair(hrow[k].y) * w3v[1];
        d += bfpair(hrow[k].z) * w3v[2];
        d += bfpair(hrow[k].w) * w3v[3];
        float xv = d.x + d.y + lf * b3[e];
        f2 xv2; xv2.x = xv; xv2.y = xv;
        #pragma unroll
        for (int q = 0; q < 4; q++) acc2[q] += xv2 * w1v[q];
    }
    if_accum(acc2, xT, w1, b3, if_cnt, if_bkt, f, lane, lf);
    ln_gelu(acc2, gamma, beta, f, h2);
}

// ---------------- one persistent fused kernel: prep + 4 layers + output ------

__global__ __launch_bounds__(256, 4) void fused(
        unsigned short* __restrict__ HsumA, unsigned short* __restrict__ HsumB,
        const float* __restrict__ x, const float* __restrict__ w1,
        const float* __restrict__ b1, const float* __restrict__ gamma,
        const float* __restrict__ beta, const float* __restrict__ w3,
        const float* __restrict__ b3, const int* __restrict__ esrc,
        const int* __restrict__ edst, int* __restrict__ if_cnt,
        int* __restrict__ if_bkt, float* __restrict__ xT,
        unsigned* __restrict__ bar, float* __restrict__ out) {
    int tid = blockIdx.x * 256 + threadIdx.x;
    int lane = threadIdx.x & 63;
    int gw = tid >> 6;                   // 0..NWAVE-1, wave-uniform

    // ---- phase 0: prep (if buckets + x transpose) ----
    if (tid < E_IF) {
        int e = E_FF + tid;
        int d = edst[e];
        int p = atomicAdd(&if_cnt[d], 1);
        if_bkt[d * IF_CAP + p] = e;
    }
    if (tid < N_IN * BATCH) {            // 128000 < 262144: single pass
        int col = tid >> 6;
        xT[col * BATCH + lane] = x[lane * N_IN + col];
    }
    gsync(bar, 1);

    // ---- layer 1: xe_0 = 0 on ff edges; Hsum_1 = h_1 -> A ----
    for (int f = gw; f < N_FUNC; f += NWAVE) {
        const f2* b1v = (const f2*)(b1 + (size_t)f * CCH);
        f2 acc2[4];
        #pragma unroll
        for (int q = 0; q < 4; q++) acc2[q] = b1v[q];
        if_accum(acc2, xT, w1, b3, if_cnt, if_bkt, f, lane, 0.0f);
        f2 h2[4];
        ln_gelu(acc2, gamma, beta, f, h2);
        uint4 o;
        o.x = bfpack2(h2[0].x, h2[0].y); o.y = bfpack2(h2[1].x, h2[1].y);
        o.z = bfpack2(h2[2].x, h2[2].y); o.w = bfpack2(h2[3].x, h2[3].y);
        *(uint4*)(HsumA + (size_t)f * HROW + lane * CCH) = o;
    }
    gsync(bar, 2);

    // ---- layer 2: A -> B (lf = 1) ----
    for (int f = gw; f < N_FUNC; f += NWAVE) {
        uint4 own = *(const uint4*)(HsumA + (size_t)f * HROW + lane * CCH);
        f2 h2[4];
        compute_h_gather(HsumA, xT, w1, b1, gamma, beta, w3, b3, esrc,
                         if_cnt, if_bkt, f, lane, 1.0f, h2);
        f2 s0 = bfpair(own.x) + h2[0];
        f2 s1 = bfpair(own.y) + h2[1];
        f2 s2 = bfpair(own.z) + h2[2];
        f2 s3 = bfpair(own.w) + h2[3];
        uint4 o;
        o.x = bfpack2(s0.x, s0.y); o.y = bfpack2(s1.x, s1.y);
        o.z = bfpack2(s2.x, s2.y); o.w = bfpack2(s3.x, s3.y);
        *(uint4*)(HsumB + (size_t)f * HROW + lane * CCH) = o;
    }
    gsync(bar, 3);

    // ---- layer 3: B -> A (lf = 2) ----
    for (int f = gw; f < N_FUNC; f += NWAVE) {
        uint4 own = *(const uint4*)(HsumB + (size_t)f * HROW + lane * CCH);
        f2 h2[4];
        compute_h_gather(HsumB, xT, w1, b1, gamma, beta, w3, b3, esrc,
                         if_cnt, if_bkt, f, lane, 2.0f, h2);
        f2 s0 = bfpair(own.x) + h2[0];
        f2 s1 = bfpair(own.y) + h2[1];
        f2 s2 = bfpair(own.z) + h2[2];
        f2 s3 = bfpair(own.w) + h2[3];
        uint4 o;
        o.x = bfpack2(s0.x, s0.y); o.y = bfpack2(s1.x, s1.y);
        o.z = bfpack2(s2.x, s2.y); o.w = bfpack2(s3.x, s3.y);
        *(uint4*)(HsumA + (size_t)f * HROW + lane * CCH) = o;
    }
    gsync(bar, 4);

    // ---- layer 4 + output: only the 2000 fo edges ----
    // out = xe_4[e]/4 = b3[e] + 0.25 * w3[p] . (Hsum_3[s] + h_4[s])
    for (int j = gw; j < N_OUT; j += NWAVE) {
        int e = E_W1 + j;
        int s = __builtin_amdgcn_readfirstlane(esrc[e]);
        uint4 own = *(const uint4*)(HsumA + (size_t)s * HROW + lane * CCH);
        f2 h2[4];
        compute_h_gather(HsumA, xT, w1, b1, gamma, beta, w3, b3, esrc,
                         if_cnt, if_bkt, s, lane, 3.0f, h2);
        f2 Hf0 = bfpair(own.x) + h2[0];
        f2 Hf1 = bfpair(own.y) + h2[1];
        f2 Hf2 = bfpair(own.z) + h2[2];
        f2 Hf3 = bfpair(own.w) + h2[3];
        int p = e - E_IF;
        const f2* w3v = (const f2*)(w3 + (size_t)p * CCH);
        f2 a = Hf0 * w3v[0];
        a += Hf1 * w3v[1];
        a += Hf2 * w3v[2];
        a += Hf3 * w3v[3];
        out[lane * N_OUT + j] = b3[e] + 0.25f * (a.x + a.y);
    }
}

// ---------------- launch ----------------

extern "C" void kernel_launch(void* const* d_in, const int* in_sizes, int n_in,
                              void* d_out, int out_size, void* d_ws, size_t ws_size,
                              hipStream_t stream) {
    const float* x      = (const float*)d_in[0];
    const float* w1_val = (const float*)d_in[1];
    const float* b1     = (const float*)d_in[2];
    const float* w3_val = (const float*)d_in[3];
    const float* b3     = (const float*)d_in[4];
    const float* gamma  = (const float*)d_in[5];
    const float* beta   = (const float*)d_in[6];
    const int* edge_src = (const int*)d_in[7];
    const int* edge_dst = (const int*)d_in[8];
    float* out = (float*)d_out;

    char* base = (char*)d_ws;
    size_t off = 0;
    auto alloc = [&](size_t bytes) -> void* {
        void* p = base + off;
        off += (bytes + 255) & ~(size_t)255;
        return p;
    };
    unsigned short* HsumA = (unsigned short*)alloc((size_t)N_FUNC * HROW * 2);  // 10.24 MB bf16
    unsigned short* HsumB = (unsigned short*)alloc((size_t)N_FUNC * HROW * 2);
    float* xT    = (float*)alloc((size_t)N_IN * BATCH * 4);
    int*   ints  = (int*)alloc((size_t)(N_FUNC + 64) * 4);   // if_cnt | bar(2 lines)
    int* if_cnt  = ints;
    unsigned* bar = (unsigned*)(ints + N_FUNC);
    int* if_bkt  = (int*)alloc((size_t)N_FUNC * IF_CAP * 4);
    (void)ws_size; (void)in_sizes; (void)n_in; (void)out_size;

    hipMemsetAsync(ints, 0, (size_t)(N_FUNC + 64) * 4, stream);   // capture-legal

    fused<<<NBLK, 256, 0, stream>>>(
        HsumA, HsumB, x, w1_val, b1, gamma, beta, w3_val, b3,
        edge_src, edge_dst, if_cnt, if_bkt, xT, bar, out);
}

// Round 8
// 192.738 us; speedup vs baseline: 2.7377x; 2.7377x over previous
//
#include <hip/hip_runtime.h>

#define N_FUNC 10000
#define N_IN   2000
#define N_OUT  2000
#define CCH    8
#define K_FF   16
#define E_FF    160000   // ff edges: dst[e] = e/16 (structural), src random func
#define E_W1    168000   // ff+if edges (dst < N_FUNC)
#define E_IF    8000
#define BATCH   64
#define EPS_LN  1e-5f
#define IF_CAP  16        // max if-in-degree of a func node (mean 0.8)
#define HROW    (BATCH * CCH)     // 512 ushorts per node total (1 KB)
#define QBATCH  16                // batch quarter
#define SLAB    (N_FUNC * QBATCH * CCH)   // ushorts per quarter slab = 2.56 MB < 4 MB XCD L2

typedef float f2 __attribute__((ext_vector_type(2)));   // -> v_pk_fma_f32

// ---- bf16 helpers (fp32 math everywhere; RNE on store) ----
__device__ __forceinline__ f2 bfpair(unsigned int u) {   // packed pair -> 2 floats
    f2 r;
    r.x = __builtin_bit_cast(float, u << 16);
    r.y = __builtin_bit_cast(float, u & 0xffff0000u);
    return r;
}
__device__ __forceinline__ unsigned int bfpack2(float f0, float f1) {
    unsigned int x0 = __builtin_bit_cast(unsigned int, f0);
    unsigned int x1 = __builtin_bit_cast(unsigned int, f1);
    unsigned int r0 = (x0 + 0x7fffu + ((x0 >> 16) & 1u)) >> 16;
    unsigned int r1 = (x1 + 0x7fffu + ((x1 >> 16) & 1u)) & 0xffff0000u;
    return r0 | r1;
}

// fast GELU (validated: absmax unchanged vs exact erf)
__device__ __forceinline__ float fast_gelu(float x) {
    float x2 = x * x;
    float u  = x * __builtin_fmaf(0.044715f, x2, 1.0f);
    float e  = exp2f(-2.3022080f * u);     // sigmoid(1.5957691*u)
    return x * (1.0f / (1.0f + e));
}

// ---------------- prep: if-edge buckets + x transpose (round-0 form) ---------

__global__ void fill_prep(const int* __restrict__ dst, const float* __restrict__ x,
                          int* __restrict__ if_cnt, int* __restrict__ if_bkt,
                          float* __restrict__ xT) {
    int i = blockIdx.x * blockDim.x + threadIdx.x;
    if (i < E_IF) {
        int e = E_FF + i;
        int d = dst[e];
        int pos = atomicAdd(&if_cnt[d], 1);
        if_bkt[d * IF_CAP + pos] = e;
    }
    if (i < N_IN * BATCH) {
        int col = i >> 6, lane = i & 63;
        xT[col * BATCH + lane] = x[lane * N_IN + col];
    }
}

// ---------------- shared pieces (lane-local over 8 channels) -----------------
// bidx = full batch index of this lane.

__device__ __forceinline__ void if_accum(
        f2* __restrict__ acc2, const float* __restrict__ xT,
        const float* __restrict__ w1, const float* __restrict__ b3,
        const int* __restrict__ if_cnt, const int* __restrict__ if_bkt,
        int f, int bidx, float lf) {
    int icnt = if_cnt[f];
    for (int j = 0; j < icnt; j++) {
        int e = if_bkt[f * IF_CAP + j];
        int ii = (e - E_FF) >> 2;
        float xv = xT[ii * BATCH + bidx] + lf * b3[e];
        f2 xv2; xv2.x = xv; xv2.y = xv;
        const f2* w1v = (const f2*)(w1 + (size_t)e * CCH);
        #pragma unroll
        for (int q = 0; q < 4; q++) acc2[q] += xv2 * w1v[q];
    }
}

__device__ __forceinline__ void ln_gelu(
        const f2* __restrict__ acc2, const float* __restrict__ gamma,
        const float* __restrict__ beta, int f, f2* __restrict__ h2) {
    float mu = 0.f;
    #pragma unroll
    for (int q = 0; q < 4; q++) mu += acc2[q].x + acc2[q].y;
    mu *= 0.125f;
    float var = 0.f;
    #pragma unroll
    for (int q = 0; q < 4; q++) {
        float dx = acc2[q].x - mu, dy = acc2[q].y - mu;
        var += dx * dx + dy * dy;
    }
    var *= 0.125f;
    float rs = rsqrtf(var + EPS_LN);
    const f2* gv = (const f2*)(gamma + (size_t)f * CCH);
    const f2* bv = (const f2*)(beta + (size_t)f * CCH);
    f2 mu2; mu2.x = mu; mu2.y = mu;
    f2 rs2; rs2.x = rs; rs2.y = rs;
    #pragma unroll
    for (int q = 0; q < 4; q++) {
        f2 g = (acc2[q] - mu2) * rs2 * gv[q] + bv[q];
        h2[q].x = fast_gelu(g.x);
        h2[q].y = fast_gelu(g.y);
    }
}

// gather-form h for (node f, quarter q): slices live in one 2.56 MB slab.
// Hq = Hold + q*SLAB; bq = batch-within-quarter; bidx = q*16+bq.
__device__ __forceinline__ void compute_h_gather_q(
        const unsigned short* __restrict__ Hq, const float* __restrict__ xT,
        const float* __restrict__ w1, const float* __restrict__ b1,
        const float* __restrict__ gamma, const float* __restrict__ beta,
        const float* __restrict__ w3, const float* __restrict__ b3,
        const int* __restrict__ esrc, const int* __restrict__ if_cnt,
        const int* __restrict__ if_bkt, int f, int bq, int bidx, float lf,
        f2* __restrict__ h2) {
    int e0 = f * K_FF;
    int srcs[K_FF];
    #pragma unroll
    for (int k = 0; k < K_FF; k++) srcs[k] = esrc[e0 + k];
    // 16 independent 256-B slice gathers (16 B/lane over 16 lanes), all in flight
    uint4 hrow[K_FF];
    #pragma unroll
    for (int k = 0; k < K_FF; k++)
        hrow[k] = *(const uint4*)(Hq + (size_t)srcs[k] * (QBATCH * CCH) + bq * CCH);

    const f2* b1v = (const f2*)(b1 + (size_t)f * CCH);
    f2 acc2[4];
    #pragma unroll
    for (int q = 0; q < 4; q++) acc2[q] = b1v[q];

    #pragma unroll
    for (int k = 0; k < K_FF; k++) {
        int e = e0 + k;
        const f2* w3v = (const f2*)(w3 + (size_t)e * CCH);   // contiguous rows
        const f2* w1v = (const f2*)(w1 + (size_t)e * CCH);
        f2 d = bfpair(hrow[k].x) * w3v[0];
        d += bfpair(hrow[k].y) * w3v[1];
        d += bfpair(hrow[k].z) * w3v[2];
        d += bfpair(hrow[k].w) * w3v[3];
        float xv = d.x + d.y + lf * b3[e];
        f2 xv2; xv2.x = xv; xv2.y = xv;
        #pragma unroll
        for (int q = 0; q < 4; q++) acc2[q] += xv2 * w1v[q];
    }
    if_accum(acc2, xT, w1, b3, if_cnt, if_bkt, f, bidx, lf);
    ln_gelu(acc2, gamma, beta, f, h2);
}

// ---------------- block 1: Hsum_1 = h_1, written in slab-major layout --------

__global__ __launch_bounds__(256, 4) void block_first(
        unsigned short* __restrict__ Hnew, const float* __restrict__ xT,
        const float* __restrict__ w1, const float* __restrict__ b1,
        const float* __restrict__ gamma, const float* __restrict__ beta,
        const float* __restrict__ b3, const int* __restrict__ if_cnt,
        const int* __restrict__ if_bkt) {
    int wid = (blockIdx.x * blockDim.x + threadIdx.x) >> 6;
    int lane = threadIdx.x & 63;          // = full batch index
    int f = __builtin_amdgcn_readfirstlane(wid);
    if (f >= N_FUNC) return;
    const f2* b1v = (const f2*)(b1 + (size_t)f * CCH);
    f2 acc2[4];
    #pragma unroll
    for (int q = 0; q < 4; q++) acc2[q] = b1v[q];
    if_accum(acc2, xT, w1, b3, if_cnt, if_bkt, f, lane, 0.0f);
    f2 h2[4];
    ln_gelu(acc2, gamma, beta, f, h2);
    uint4 o;
    o.x = bfpack2(h2[0].x, h2[0].y); o.y = bfpack2(h2[1].x, h2[1].y);
    o.z = bfpack2(h2[2].x, h2[2].y); o.w = bfpack2(h2[3].x, h2[3].y);
    int q = lane >> 4, bq = lane & 15;    // slab-major: [q][f][bq][ch]
    *(uint4*)(Hnew + (size_t)q * SLAB + (size_t)f * (QBATCH * CCH) + bq * CCH) = o;
}

// ---------------- blocks 2,3: quarter-pinned gather mids ---------------------
// blockIdx%8 ~ XCD (round-robin); XCD pair {2q,2q+1} owns quarter q ->
// each XCD's L2 caches only its 2.56 MB slab.

__global__ __launch_bounds__(256, 4) void block_mid_q(
        const unsigned short* __restrict__ Hold, unsigned short* __restrict__ Hnew,
        const float* __restrict__ xT, const float* __restrict__ w1,
        const float* __restrict__ b1, const float* __restrict__ gamma,
        const float* __restrict__ beta, const float* __restrict__ w3,
        const float* __restrict__ b3, const int* __restrict__ esrc,
        const int* __restrict__ if_cnt, const int* __restrict__ if_bkt, float lf) {
    int blk  = blockIdx.x;
    int xcd  = blk & 7;
    int q    = xcd >> 1;
    int l    = ((blk >> 3) << 1) | (xcd & 1);         // 0..625 within quarter
    int lane = threadIdx.x & 63;
    int f    = l * 16 + ((threadIdx.x >> 6) << 2) + (lane >> 4);
    int bq   = lane & 15;
    int bidx = q * QBATCH + bq;
    if (f >= N_FUNC) return;
    const unsigned short* Hq = Hold + (size_t)q * SLAB;
    size_t oidx = (size_t)q * SLAB + (size_t)f * (QBATCH * CCH) + bq * CCH;
    uint4 own = *(const uint4*)(Hold + oidx);          // own slice, issued early
    f2 h2[4];
    compute_h_gather_q(Hq, xT, w1, b1, gamma, beta, w3, b3, esrc,
                       if_cnt, if_bkt, f, bq, bidx, lf, h2);
    f2 s0 = bfpair(own.x) + h2[0];
    f2 s1 = bfpair(own.y) + h2[1];
    f2 s2 = bfpair(own.z) + h2[2];
    f2 s3 = bfpair(own.w) + h2[3];
    uint4 o;
    o.x = bfpack2(s0.x, s0.y); o.y = bfpack2(s1.x, s1.y);
    o.z = bfpack2(s2.x, s2.y); o.w = bfpack2(s3.x, s3.y);
    *(uint4*)(Hnew + oidx) = o;
}

// ---------------- block 4 + output: quarter-pinned, only 2000 fo edges -------
// out = xe_4[e]/4 = b3[e] + 0.25 * w3[p] . (Hsum_3[s] + h_4[s])

__global__ __launch_bounds__(256, 4) void block_out_q(
        const unsigned short* __restrict__ Hold, const float* __restrict__ xT,
        const float* __restrict__ w1, const float* __restrict__ b1,
        const float* __restrict__ gamma, const float* __restrict__ beta,
        const float* __restrict__ w3, const float* __restrict__ b3,
        const int* __restrict__ esrc, const int* __restrict__ if_cnt,
        const int* __restrict__ if_bkt, float* __restrict__ out) {
    int blk  = blockIdx.x;
    int xcd  = blk & 7;
    int q    = xcd >> 1;
    int l    = ((blk >> 3) << 1) | (xcd & 1);         // 0..127 within quarter
    int lane = threadIdx.x & 63;
    int j    = l * 16 + ((threadIdx.x >> 6) << 2) + (lane >> 4);
    int bq   = lane & 15;
    int bidx = q * QBATCH + bq;
    if (j >= N_OUT) return;
    int e = E_W1 + j;
    int s = esrc[e];                                   // per-lane-group
    const unsigned short* Hq = Hold + (size_t)q * SLAB;
    uint4 own = *(const uint4*)(Hq + (size_t)s * (QBATCH * CCH) + bq * CCH);
    f2 h2[4];
    compute_h_gather_q(Hq, xT, w1, b1, gamma, beta, w3, b3, esrc,
                       if_cnt, if_bkt, s, bq, bidx, 3.0f, h2);
    f2 Hf0 = bfpair(own.x) + h2[0];
    f2 Hf1 = bfpair(own.y) + h2[1];
    f2 Hf2 = bfpair(own.z) + h2[2];
    f2 Hf3 = bfpair(own.w) + h2[3];
    int p = e - E_IF;
    const f2* w3v = (const f2*)(w3 + (size_t)p * CCH);
    f2 a = Hf0 * w3v[0];
    a += Hf1 * w3v[1];
    a += Hf2 * w3v[2];
    a += Hf3 * w3v[3];
    out[(size_t)bidx * N_OUT + j] = b3[e] + 0.25f * (a.x + a.y);
}

// ---------------- launch ----------------

extern "C" void kernel_launch(void* const* d_in, const int* in_sizes, int n_in,
                              void* d_out, int out_size, void* d_ws, size_t ws_size,
                              hipStream_t stream) {
    const float* x      = (const float*)d_in[0];
    const float* w1_val = (const float*)d_in[1];
    const float* b1     = (const float*)d_in[2];
    const float* w3_val = (const float*)d_in[3];
    const float* b3     = (const float*)d_in[4];
    const float* gamma  = (const float*)d_in[5];
    const float* beta   = (const float*)d_in[6];
    const int* edge_src = (const int*)d_in[7];
    const int* edge_dst = (const int*)d_in[8];
    float* out = (float*)d_out;

    char* base = (char*)d_ws;
    size_t off = 0;
    auto alloc = [&](size_t bytes) -> void* {
        void* p = base + off;
        off += (bytes + 255) & ~(size_t)255;
        return p;
    };
    unsigned short* HsumA = (unsigned short*)alloc((size_t)N_FUNC * HROW * 2);  // 4 slabs, 10.24 MB
    unsigned short* HsumB = (unsigned short*)alloc((size_t)N_FUNC * HROW * 2);
    float* xT    = (float*)alloc((size_t)N_IN * BATCH * 4);
    int* if_cnt  = (int*)alloc(N_FUNC * 4);
    int* if_bkt  = (int*)alloc((size_t)N_FUNC * IF_CAP * 4);
    (void)ws_size; (void)in_sizes; (void)n_in; (void)out_size;

    hipMemsetAsync(if_cnt, 0, N_FUNC * 4, stream);   // capture-legal

    fill_prep<<<(N_IN * BATCH + 255) / 256, 256, 0, stream>>>(
        edge_dst, x, if_cnt, if_bkt, xT);

    // block 1: Hsum_1 = h_1 -> A  (slab-major write)
    block_first<<<(N_FUNC * BATCH) / 256, 256, 0, stream>>>(
        HsumA, xT, w1_val, b1, gamma, beta, b3, if_cnt, if_bkt);

    // block 2: A -> B (lf = 1); 2504 blocks: 313 per xcd, quarter = xcd/2
    block_mid_q<<<2504, 256, 0, stream>>>(
        HsumA, HsumB, xT, w1_val, b1, gamma, beta, w3_val, b3,
        edge_src, if_cnt, if_bkt, 1.0f);

    // block 3: B -> A (lf = 2)
    block_mid_q<<<2504, 256, 0, stream>>>(
        HsumB, HsumA, xT, w1_val, b1, gamma, beta, w3_val, b3,
        edge_src, if_cnt, if_bkt, 2.0f);

    // block 4 + output: reads Hsum_3 = A (lf = 3); 512 blocks, quarter-pinned
    block_out_q<<<512, 256, 0, stream>>>(
        HsumA, xT, w1_val, b1, gamma, beta, w3_val, b3,
        edge_src, if_cnt, if_bkt, out);
}